// Round 2
// 2671.583 us; speedup vs baseline: 1.5157x; 1.5157x over previous
//
#include <hip/hip_runtime.h>
#include <math.h>

#define NT 64
#define NB 1024
#define NC 512
#define HH 512
#define EE 128
#define NCLS 97
#define STEPS 32

// LDS row stride in bytes for 32-bf16 (64B) rows, +16B pad: 2-way banks (free)
#define LDSW 80

typedef __bf16 bf16_t;
typedef bf16_t bf16x8 __attribute__((ext_vector_type(8)));
typedef float f32x4 __attribute__((ext_vector_type(4)));
typedef unsigned short u16x8 __attribute__((ext_vector_type(8)));

__device__ __forceinline__ float fast_tanh(float x) {
  float e = __expf(2.f * x);
  return 1.f - 2.f / (e + 1.f);
}
__device__ __forceinline__ float fast_sig(float x) {
  return 1.f / (1.f + __expf(-x));
}

// ---- fp32 -> (hi,lo) bf16 split: x ~= hi + lo, |err| ~ 2^-17 |x|
__device__ __forceinline__ unsigned short bf16_rne(float x) {
  unsigned u = __float_as_uint(x);
  unsigned r = u + 0x7FFFu + ((u >> 16) & 1u);
  return (unsigned short)(r >> 16);
}
__device__ __forceinline__ void split2(float x, unsigned short& h,
                                       unsigned short& l) {
  unsigned u = __float_as_uint(x);
  h = (unsigned short)(u >> 16);  // truncation; residual captured by lo
  float hf = __uint_as_float(u & 0xFFFF0000u);
  l = bf16_rne(x - hf);
}

// ---------------- big GEMM via split-bf16 MFMA:
// C[M,N] = A[M,K](fp32) @ B[N,K]^T (pre-split hi/lo bf16).
// 128x128 tile, 4 waves (64x64 each), BK=32, reg-prefetch dbuf.
__global__ __launch_bounds__(256) void gemm_mfma_big(
    const float* __restrict__ A, const unsigned short* __restrict__ Bhg,
    const unsigned short* __restrict__ Blg, float* __restrict__ C, int N,
    int K) {
  __shared__ __attribute__((aligned(16))) char Ah[128 * LDSW];
  __shared__ __attribute__((aligned(16))) char Al[128 * LDSW];
  __shared__ __attribute__((aligned(16))) char Bh[128 * LDSW];
  __shared__ __attribute__((aligned(16))) char Bl[128 * LDSW];
  const int bm = blockIdx.y * 128;
  const int bn = blockIdx.x * 128;
  const int tid = threadIdx.x;
  const int sr = tid >> 1;          // staging row 0..127
  const int sq = (tid & 1) * 16;    // k-element offset 0/16
  const int lane = tid & 63, wid = tid >> 6;
  const int wm = (wid >> 1) * 64, wn = (wid & 1) * 64;
  const int lr = lane & 15;
  const int ks = (lane >> 4) * 16;  // fragment k-byte slot

  const float* Ap = A + (size_t)(bm + sr) * K + sq;
  const unsigned short* Bph = Bhg + (size_t)(bn + sr) * K + sq;
  const unsigned short* Bpl = Blg + (size_t)(bn + sr) * K + sq;

  f32x4 acc[4][4];
  f32x4 z;
  z[0] = 0.f; z[1] = 0.f; z[2] = 0.f; z[3] = 0.f;
#pragma unroll
  for (int i = 0; i < 4; ++i)
#pragma unroll
    for (int j = 0; j < 4; ++j) acc[i][j] = z;

  float4 pa[4];
  u16x8 pbh[2], pbl[2];
#pragma unroll
  for (int f = 0; f < 4; ++f) pa[f] = *(const float4*)(Ap + f * 4);
#pragma unroll
  for (int g = 0; g < 2; ++g) {
    pbh[g] = *(const u16x8*)(Bph + g * 8);
    pbl[g] = *(const u16x8*)(Bpl + g * 8);
  }

  for (int k0 = 0; k0 < K; k0 += 32) {
#pragma unroll
    for (int f = 0; f < 4; ++f) {
      ushort4 h4, l4;
      split2(pa[f].x, h4.x, l4.x);
      split2(pa[f].y, h4.y, l4.y);
      split2(pa[f].z, h4.z, l4.z);
      split2(pa[f].w, h4.w, l4.w);
      int off = sr * LDSW + sq * 2 + f * 8;
      *(ushort4*)(Ah + off) = h4;
      *(ushort4*)(Al + off) = l4;
    }
#pragma unroll
    for (int g = 0; g < 2; ++g) {
      int off = sr * LDSW + sq * 2 + g * 16;
      *(u16x8*)(Bh + off) = pbh[g];
      *(u16x8*)(Bl + off) = pbl[g];
    }
    __syncthreads();
    if (k0 + 32 < K) {
#pragma unroll
      for (int f = 0; f < 4; ++f)
        pa[f] = *(const float4*)(Ap + k0 + 32 + f * 4);
#pragma unroll
      for (int g = 0; g < 2; ++g) {
        pbh[g] = *(const u16x8*)(Bph + k0 + 32 + g * 8);
        pbl[g] = *(const u16x8*)(Bpl + k0 + 32 + g * 8);
      }
    }
    bf16x8 a_h[4], a_l[4], b_h[4], b_l[4];
#pragma unroll
    for (int mf = 0; mf < 4; ++mf) {
      int ro = (wm + mf * 16 + lr) * LDSW + ks;
      a_h[mf] = *(const bf16x8*)(Ah + ro);
      a_l[mf] = *(const bf16x8*)(Al + ro);
    }
#pragma unroll
    for (int nf = 0; nf < 4; ++nf) {
      int ro = (wn + nf * 16 + lr) * LDSW + ks;
      b_h[nf] = *(const bf16x8*)(Bh + ro);
      b_l[nf] = *(const bf16x8*)(Bl + ro);
    }
    // 3-term split: hi*hi, hi*lo, lo*hi; term-major for dep distance 16
#pragma unroll
    for (int mf = 0; mf < 4; ++mf)
#pragma unroll
      for (int nf = 0; nf < 4; ++nf)
        acc[mf][nf] = __builtin_amdgcn_mfma_f32_16x16x32_bf16(
            a_h[mf], b_h[nf], acc[mf][nf], 0, 0, 0);
#pragma unroll
    for (int mf = 0; mf < 4; ++mf)
#pragma unroll
      for (int nf = 0; nf < 4; ++nf)
        acc[mf][nf] = __builtin_amdgcn_mfma_f32_16x16x32_bf16(
            a_h[mf], b_l[nf], acc[mf][nf], 0, 0, 0);
#pragma unroll
    for (int mf = 0; mf < 4; ++mf)
#pragma unroll
      for (int nf = 0; nf < 4; ++nf)
        acc[mf][nf] = __builtin_amdgcn_mfma_f32_16x16x32_bf16(
            a_l[mf], b_h[nf], acc[mf][nf], 0, 0, 0);
    __syncthreads();
  }
  // D layout: col = lane&15, row = (lane>>4)*4 + reg
#pragma unroll
  for (int mf = 0; mf < 4; ++mf) {
    int row0 = bm + wm + mf * 16 + (lane >> 4) * 4;
#pragma unroll
    for (int nf = 0; nf < 4; ++nf) {
      int col = bn + wn + nf * 16 + lr;
      float* Cp = C + (size_t)row0 * N + col;
      Cp[0] = acc[mf][nf][0];
      Cp[N] = acc[mf][nf][1];
      Cp[2 * N] = acc[mf][nf][2];
      Cp[3 * N] = acc[mf][nf][3];
    }
  }
}

// ---------------- step GEMM via split-bf16 MFMA, K=512 split in halves
// (blockIdx.z), active-row gating, optional bias. 64x128 tile, 4 waves
// (32x64 each), BK=32.
__global__ __launch_bounds__(256) void gemm_mfma_step(
    const float* __restrict__ A, int lda, const unsigned short* __restrict__ Bhg,
    const unsigned short* __restrict__ Blg, const float* __restrict__ bias,
    float* __restrict__ Ca, float* __restrict__ Cb, int ldc,
    const int* __restrict__ cnt, int step) {
  const int bm = blockIdx.y * 64;
  if (bm >= cnt[step]) return;
  __shared__ __attribute__((aligned(16))) char Ah[64 * LDSW];
  __shared__ __attribute__((aligned(16))) char Al[64 * LDSW];
  __shared__ __attribute__((aligned(16))) char Bh[128 * LDSW];
  __shared__ __attribute__((aligned(16))) char Bl[128 * LDSW];
  const int kh = blockIdx.z;
  const int kbase = kh * 256;
  float* __restrict__ C = kh ? Cb : Ca;
  const int bn = blockIdx.x * 128;
  const int tid = threadIdx.x;
  const int ar = tid >> 2, aq = (tid & 3) * 8;   // A: 64 rows x 32k
  const int br = tid >> 1, bq = (tid & 1) * 16;  // B: 128 rows x 32k
  const int lane = tid & 63, wid = tid >> 6;
  const int wm = (wid >> 1) * 32, wn = (wid & 1) * 64;
  const int lr = lane & 15;
  const int ks = (lane >> 4) * 16;

  const float* Ap = A + (size_t)(bm + ar) * lda + kbase + aq;
  const unsigned short* Bph = Bhg + (size_t)(bn + br) * 512 + kbase + bq;
  const unsigned short* Bpl = Blg + (size_t)(bn + br) * 512 + kbase + bq;

  f32x4 acc[2][4];
  f32x4 z;
  z[0] = 0.f; z[1] = 0.f; z[2] = 0.f; z[3] = 0.f;
#pragma unroll
  for (int i = 0; i < 2; ++i)
#pragma unroll
    for (int j = 0; j < 4; ++j) acc[i][j] = z;

  float4 pa[2];
  u16x8 pbh[2], pbl[2];
  pa[0] = *(const float4*)(Ap);
  pa[1] = *(const float4*)(Ap + 4);
#pragma unroll
  for (int g = 0; g < 2; ++g) {
    pbh[g] = *(const u16x8*)(Bph + g * 8);
    pbl[g] = *(const u16x8*)(Bpl + g * 8);
  }

  for (int k0 = 0; k0 < 256; k0 += 32) {
#pragma unroll
    for (int f = 0; f < 2; ++f) {
      ushort4 h4, l4;
      float4 v = pa[f];
      split2(v.x, h4.x, l4.x);
      split2(v.y, h4.y, l4.y);
      split2(v.z, h4.z, l4.z);
      split2(v.w, h4.w, l4.w);
      int off = ar * LDSW + aq * 2 + f * 8;
      *(ushort4*)(Ah + off) = h4;
      *(ushort4*)(Al + off) = l4;
    }
#pragma unroll
    for (int g = 0; g < 2; ++g) {
      int off = br * LDSW + bq * 2 + g * 16;
      *(u16x8*)(Bh + off) = pbh[g];
      *(u16x8*)(Bl + off) = pbl[g];
    }
    __syncthreads();
    if (k0 + 32 < 256) {
      pa[0] = *(const float4*)(Ap + k0 + 32);
      pa[1] = *(const float4*)(Ap + k0 + 36);
#pragma unroll
      for (int g = 0; g < 2; ++g) {
        pbh[g] = *(const u16x8*)(Bph + k0 + 32 + g * 8);
        pbl[g] = *(const u16x8*)(Bpl + k0 + 32 + g * 8);
      }
    }
    bf16x8 a_h[2], a_l[2], b_h[4], b_l[4];
#pragma unroll
    for (int mf = 0; mf < 2; ++mf) {
      int ro = (wm + mf * 16 + lr) * LDSW + ks;
      a_h[mf] = *(const bf16x8*)(Ah + ro);
      a_l[mf] = *(const bf16x8*)(Al + ro);
    }
#pragma unroll
    for (int nf = 0; nf < 4; ++nf) {
      int ro = (wn + nf * 16 + lr) * LDSW + ks;
      b_h[nf] = *(const bf16x8*)(Bh + ro);
      b_l[nf] = *(const bf16x8*)(Bl + ro);
    }
#pragma unroll
    for (int mf = 0; mf < 2; ++mf)
#pragma unroll
      for (int nf = 0; nf < 4; ++nf)
        acc[mf][nf] = __builtin_amdgcn_mfma_f32_16x16x32_bf16(
            a_h[mf], b_h[nf], acc[mf][nf], 0, 0, 0);
#pragma unroll
    for (int mf = 0; mf < 2; ++mf)
#pragma unroll
      for (int nf = 0; nf < 4; ++nf)
        acc[mf][nf] = __builtin_amdgcn_mfma_f32_16x16x32_bf16(
            a_h[mf], b_l[nf], acc[mf][nf], 0, 0, 0);
#pragma unroll
    for (int mf = 0; mf < 2; ++mf)
#pragma unroll
      for (int nf = 0; nf < 4; ++nf)
        acc[mf][nf] = __builtin_amdgcn_mfma_f32_16x16x32_bf16(
            a_l[mf], b_h[nf], acc[mf][nf], 0, 0, 0);
    __syncthreads();
  }
  float bc[4] = {0.f, 0.f, 0.f, 0.f};
  if (bias && kh == 0) {
#pragma unroll
    for (int nf = 0; nf < 4; ++nf) bc[nf] = bias[bn + wn + nf * 16 + lr];
  }
#pragma unroll
  for (int mf = 0; mf < 2; ++mf) {
    int row0 = bm + wm + mf * 16 + (lane >> 4) * 4;
#pragma unroll
    for (int nf = 0; nf < 4; ++nf) {
      int col = bn + wn + nf * 16 + lr;
      float* Cp = C + (size_t)row0 * ldc + col;
      Cp[0] = acc[mf][nf][0] + bc[nf];
      Cp[ldc] = acc[mf][nf][1] + bc[nf];
      Cp[2 * ldc] = acc[mf][nf][2] + bc[nf];
      Cp[3 * ldc] = acc[mf][nf][3] + bc[nf];
    }
  }
}

// ---------------- fused e + softmax + context; block i = compacted index
__global__ __launch_bounds__(512) void step_attn2(
    const float* __restrict__ fp, const float* __restrict__ C1a,
    const float* __restrict__ C1b, const float* __restrict__ w_score,
    const float* __restrict__ feats, float* __restrict__ context,
    const int* __restrict__ perm, const int* __restrict__ cnt, int step) {
  const int i0 = blockIdx.x;
  if (i0 >= cnt[step]) return;
  __shared__ float es[NT];
  __shared__ float als[NT];
  const int b = perm[i0];
  const int tid = threadIdx.x;
  const int lane = tid & 63, wid = tid >> 6;
  const float* hpa = C1a + (size_t)i0 * 2048 + lane * 8;
  const float* hpb = C1b + (size_t)i0 * 2048 + lane * 8;
  float4 ha0 = *(const float4*)hpa;
  float4 ha1 = *(const float4*)(hpa + 4);
  float4 hb0 = *(const float4*)hpb;
  float4 hb1 = *(const float4*)(hpb + 4);
  float4 h0, h1;
  h0.x = ha0.x + hb0.x; h0.y = ha0.y + hb0.y;
  h0.z = ha0.z + hb0.z; h0.w = ha0.w + hb0.w;
  h1.x = ha1.x + hb1.x; h1.y = ha1.y + hb1.y;
  h1.z = ha1.z + hb1.z; h1.w = ha1.w + hb1.w;
  float4 w0 = *(const float4*)(w_score + lane * 8);
  float4 w1 = *(const float4*)(w_score + lane * 8 + 4);
#pragma unroll
  for (int pass = 0; pass < 2; ++pass) {
    float4 f0[4], f1[4];
#pragma unroll
    for (int i = 0; i < 4; ++i) {
      int t = wid * 8 + pass * 4 + i;
      const float* fr = fp + ((size_t)t * NB + b) * HH + lane * 8;
      f0[i] = *(const float4*)fr;
      f1[i] = *(const float4*)(fr + 4);
    }
#pragma unroll
    for (int i = 0; i < 4; ++i) {
      float acc = 0.f;
      acc += fast_tanh(f0[i].x + h0.x) * w0.x;
      acc += fast_tanh(f0[i].y + h0.y) * w0.y;
      acc += fast_tanh(f0[i].z + h0.z) * w0.z;
      acc += fast_tanh(f0[i].w + h0.w) * w0.w;
      acc += fast_tanh(f1[i].x + h1.x) * w1.x;
      acc += fast_tanh(f1[i].y + h1.y) * w1.y;
      acc += fast_tanh(f1[i].z + h1.z) * w1.z;
      acc += fast_tanh(f1[i].w + h1.w) * w1.w;
#pragma unroll
      for (int off = 32; off > 0; off >>= 1) acc += __shfl_down(acc, off, 64);
      if (lane == 0) es[wid * 8 + pass * 4 + i] = acc;
    }
  }
  __syncthreads();
  if (tid < 64) {
    float v = es[tid];
    float mx = v;
#pragma unroll
    for (int off = 32; off > 0; off >>= 1) mx = fmaxf(mx, __shfl_xor(mx, off, 64));
    float p = __expf(v - mx);
    float sum = p;
#pragma unroll
    for (int off = 32; off > 0; off >>= 1) sum += __shfl_xor(sum, off, 64);
    als[tid] = p / sum;
  }
  __syncthreads();
  float a0 = 0.f, a1 = 0.f, a2 = 0.f, a3 = 0.f;
  const float* fb = feats + (size_t)b * NC + tid;
#pragma unroll 4
  for (int t = 0; t < NT; t += 4) {
    a0 += als[t + 0] * fb[(size_t)(t + 0) * NB * NC];
    a1 += als[t + 1] * fb[(size_t)(t + 1) * NB * NC];
    a2 += als[t + 2] * fb[(size_t)(t + 2) * NB * NC];
    a3 += als[t + 3] * fb[(size_t)(t + 3) * NB * NC];
  }
  context[(size_t)i0 * NC + tid] = ((a0 + a1) + (a2 + a3));
}

// ---------------- fused GRU gates + logits + argmax; block i = compacted idx
__global__ __launch_bounds__(128) void step_update2(
    const float* __restrict__ C1a, const float* __restrict__ C1b,
    const float* __restrict__ Ga, const float* __restrict__ Gb,
    const float* __restrict__ P, const float* __restrict__ hc,
    float* __restrict__ hn_out, const float* __restrict__ w_gen,
    const float* __restrict__ b_gen, const int* __restrict__ offs,
    float* __restrict__ out, int* __restrict__ tgt,
    const int* __restrict__ perm, const int* __restrict__ cnt, int step) {
  const int i0 = blockIdx.x;
  if (i0 >= cnt[step]) return;
  __shared__ float hs[HH];
  __shared__ float lv[128];
  __shared__ int li[128];
  const int b = perm[i0];
  const int tid = threadIdx.x;
  const int tg = tgt[b];
  const float* gia = Ga + (size_t)i0 * 1536;
  const float* gib = Gb + (size_t)i0 * 1536;
  const float* Pb = P + (size_t)tg * 1536;
  const float* gha = C1a + (size_t)i0 * 2048 + 512;
  const float* ghb = C1b + (size_t)i0 * 2048 + 512;
#pragma unroll
  for (int i = 0; i < 4; ++i) {
    int j = tid + i * 128;
    float ir = gia[j] + gib[j] + Pb[j];
    float iz = gia[512 + j] + gib[512 + j] + Pb[512 + j];
    float in = gia[1024 + j] + gib[1024 + j] + Pb[1024 + j];
    float hr = gha[j] + ghb[j];
    float hz = gha[512 + j] + ghb[512 + j];
    float hnv = gha[1024 + j] + ghb[1024 + j];
    float r = fast_sig(ir + hr);
    float z = fast_sig(iz + hz);
    float n = fast_tanh(in + r * hnv);
    float h = hc[(size_t)i0 * HH + j];
    float hv = (1.f - z) * n + z * h;
    hs[j] = hv;
    hn_out[(size_t)i0 * HH + j] = hv;
  }
  __syncthreads();
  float acc = -INFINITY;
  if (tid < NCLS) {
    const float4* wr4 = (const float4*)(w_gen + (size_t)tid * HH);
    float s = 0.f;
    for (int k = 0; k < HH / 4; ++k) {
      float4 w = wr4[k];
      s += hs[4 * k + 0] * w.x + hs[4 * k + 1] * w.y +
           hs[4 * k + 2] * w.z + hs[4 * k + 3] * w.w;
    }
    acc = s + b_gen[tid];
    out[(size_t)(offs[b] + step) * NCLS + tid] = acc;  // active => step < tl[b]
  }
  lv[tid] = acc;
  li[tid] = tid;
  __syncthreads();
  for (int d = 64; d > 0; d >>= 1) {
    if (tid < d) {
      float v2 = lv[tid + d];
      int i2 = li[tid + d];
      if (v2 > lv[tid] || (v2 == lv[tid] && i2 < li[tid])) {
        lv[tid] = v2;
        li[tid] = i2;
      }
    }
    __syncthreads();
  }
  if (tid == 0) tgt[b] = li[0] + 1;
}

// ---------------- one-time setup kernels
__global__ __launch_bounds__(1024) void sort_tl(const int* __restrict__ tl,
                                                int* __restrict__ perm,
                                                int* __restrict__ cnt,
                                                int* __restrict__ offs) {
  __shared__ int s[NB];
  const int t = threadIdx.x;
  s[t] = tl[t];
  __syncthreads();
  const int myv = s[t];
  int pos = 0;
  int pre = 0;
  for (int b = 0; b < NB; ++b) {
    int v = s[b];
    pos += (v > myv || (v == myv && b < t)) ? 1 : 0;
    pre += (b < t) ? v : 0;
  }
  perm[pos] = t;
  offs[t] = pre;
  if (t < STEPS) {
    int c = 0;
    for (int b = 0; b < NB; ++b) c += (s[b] > t) ? 1 : 0;
    cnt[t] = c;
  }
}

__global__ __launch_bounds__(256) void build_P(
    const float* __restrict__ char_emb, const float* __restrict__ w_ih,
    const float* __restrict__ b_ih, float* __restrict__ P) {
  __shared__ float emb[EE];
  int c = blockIdx.x;
  int tid = threadIdx.x;
  if (tid < EE) emb[tid] = char_emb[c * EE + tid];
  __syncthreads();
  for (int j = tid; j < 3 * HH; j += 256) {
    const float* wr = w_ih + (size_t)j * (NC + EE) + NC;
    float s = 0.f;
    for (int k = 0; k < EE; ++k) s += emb[k] * wr[k];
    P[(size_t)c * 1536 + j] = s + b_ih[j];
  }
}

__global__ __launch_bounds__(256) void build_wcat(
    const float* __restrict__ w_h2h, const float* __restrict__ w_hh,
    const float* __restrict__ b_h2h, const float* __restrict__ b_hh,
    float* __restrict__ Wcat, float* __restrict__ bcat) {
  int idx = blockIdx.x * 256 + threadIdx.x;  // float4 index, 2048*512/4 total
  const int n1 = 512 * 512 / 4;
  float4* dst = (float4*)Wcat;
  if (idx < n1)
    dst[idx] = ((const float4*)w_h2h)[idx];
  else
    dst[idx] = ((const float4*)w_hh)[idx - n1];
  if (idx < 2048) bcat[idx] = (idx < 512) ? b_h2h[idx] : b_hh[idx - 512];
}

// split fp32 [rows][ld] (first 512 cols) into dense hi/lo bf16 [rows][512]
__global__ __launch_bounds__(256) void split512(
    const float* __restrict__ src, int ld, unsigned short* __restrict__ hi,
    unsigned short* __restrict__ lo, int rows) {
  int idx = blockIdx.x * 256 + threadIdx.x;
  if (idx >= rows * 512) return;
  int r = idx >> 9, c = idx & 511;
  float x = src[(size_t)r * ld + c];
  unsigned short h, l;
  split2(x, h, l);
  hi[idx] = h;
  lo[idx] = l;
}

__global__ __launch_bounds__(256) void init_kernel(float* __restrict__ h0,
                                                   int* __restrict__ tgt) {
  int idx = blockIdx.x * 256 + threadIdx.x;
  if (idx < NB * HH) h0[idx] = 0.f;
  if (idx < NB) tgt[idx] = 0;
}

extern "C" void kernel_launch(void* const* d_in, const int* in_sizes, int n_in,
                              void* d_out, int out_size, void* d_ws,
                              size_t ws_size, hipStream_t stream) {
  const float* feats = (const float*)d_in[0];
  const float* w_i2h = (const float*)d_in[1];
  const float* w_h2h = (const float*)d_in[2];
  const float* b_h2h = (const float*)d_in[3];
  const float* w_score = (const float*)d_in[4];
  const float* w_ih = (const float*)d_in[5];
  const float* w_hh = (const float*)d_in[6];
  const float* b_ih = (const float*)d_in[7];
  const float* b_hh = (const float*)d_in[8];
  const float* char_emb = (const float*)d_in[9];
  const float* w_gen = (const float*)d_in[10];
  const float* b_gen = (const float*)d_in[11];
  const int* tl = (const int*)d_in[12];
  float* out = (float*)d_out;

  char* ws = (char*)d_ws;
  float* fp = (float*)ws;      ws += (size_t)NT * NB * HH * 4;  // 134 MB
  float* C1a = (float*)ws;     ws += (size_t)NB * 2048 * 4;
  float* C1b = (float*)ws;     ws += (size_t)NB * 2048 * 4;
  float* Ga = (float*)ws;      ws += (size_t)NB * 1536 * 4;
  float* Gb = (float*)ws;      ws += (size_t)NB * 1536 * 4;
  float* context = (float*)ws; ws += (size_t)NB * NC * 4;
  float* h0 = (float*)ws;      ws += (size_t)NB * HH * 4;
  float* h1 = (float*)ws;      ws += (size_t)NB * HH * 4;
  float* Wcat = (float*)ws;    ws += (size_t)2048 * 512 * 4;
  float* bcat = (float*)ws;    ws += 2048 * 4;
  float* P = (float*)ws;       ws += (size_t)98 * 1536 * 4;
  unsigned short* Wi_h = (unsigned short*)ws; ws += (size_t)512 * 512 * 2;
  unsigned short* Wi_l = (unsigned short*)ws; ws += (size_t)512 * 512 * 2;
  unsigned short* Wc_h = (unsigned short*)ws; ws += (size_t)2048 * 512 * 2;
  unsigned short* Wc_l = (unsigned short*)ws; ws += (size_t)2048 * 512 * 2;
  unsigned short* Wg_h = (unsigned short*)ws; ws += (size_t)1536 * 512 * 2;
  unsigned short* Wg_l = (unsigned short*)ws; ws += (size_t)1536 * 512 * 2;
  int* tgt = (int*)ws;         ws += 4096;
  int* offs = (int*)ws;        ws += 4096;
  int* perm = (int*)ws;        ws += 4096;
  int* cnt = (int*)ws;         ws += 4096;

  hipLaunchKernelGGL(sort_tl, dim3(1), dim3(1024), 0, stream, tl, perm, cnt,
                     offs);
  hipLaunchKernelGGL(init_kernel, dim3((NB * HH) / 256), dim3(256), 0, stream,
                     h0, tgt);
  hipLaunchKernelGGL(build_wcat, dim3(1024), dim3(256), 0, stream, w_h2h, w_hh,
                     b_h2h, b_hh, Wcat, bcat);
  hipLaunchKernelGGL(build_P, dim3(98), dim3(256), 0, stream, char_emb, w_ih,
                     b_ih, P);
  // pre-split constant B matrices into hi/lo bf16 planes
  hipLaunchKernelGGL(split512, dim3(512 * 2), dim3(256), 0, stream, w_i2h, 512,
                     Wi_h, Wi_l, 512);
  hipLaunchKernelGGL(split512, dim3(2048 * 2), dim3(256), 0, stream, Wcat, 512,
                     Wc_h, Wc_l, 2048);
  hipLaunchKernelGGL(split512, dim3(1536 * 2), dim3(256), 0, stream, w_ih, 640,
                     Wg_h, Wg_l, 1536);
  // fp = feats @ w_i2h^T  [65536, 512] via split-bf16 MFMA
  hipLaunchKernelGGL(gemm_mfma_big, dim3(HH / 128, (NT * NB) / 128), dim3(256),
                     0, stream, feats, Wi_h, Wi_l, fp, HH, NC);

  float* hbuf[2] = {h0, h1};
  for (int s = 0; s < STEPS; ++s) {
    float* hc = hbuf[s & 1];
    float* hn = hbuf[(s + 1) & 1];
    // C1 = hcomp @ Wcat^T + bcat   [cnt(s),2048], K-split-2
    hipLaunchKernelGGL(gemm_mfma_step, dim3(2048 / 128, NB / 64, 2), dim3(256),
                       0, stream, hc, HH, Wc_h, Wc_l, bcat, C1a, C1b, 2048,
                       cnt, s);
    hipLaunchKernelGGL(step_attn2, dim3(NB), dim3(512), 0, stream, fp, C1a,
                       C1b, w_score, feats, context, perm, cnt, s);
    // gi = context @ w_ih[:, :512]^T   [cnt(s),1536], K-split-2
    hipLaunchKernelGGL(gemm_mfma_step, dim3(1536 / 128, NB / 64, 2), dim3(256),
                       0, stream, context, NC, Wg_h, Wg_l,
                       (const float*)nullptr, Ga, Gb, 1536, cnt, s);
    hipLaunchKernelGGL(step_update2, dim3(NB), dim3(128), 0, stream, C1a, C1b,
                       Ga, Gb, P, hc, hn, w_gen, b_gen, offs, out, tgt, perm,
                       cnt, s);
  }
}